// Round 1
// baseline (1535.451 us; speedup 1.0000x reference)
//
#include <hip/hip_runtime.h>

static constexpr int BTRIALS = 32;
static constexpr int TSTEPS  = 512;
static constexpr int IDIM    = 64;
static constexpr int NDIM    = 4096;
static constexpr int RDIM    = 8;
static constexpr int ODIM    = 64;

__device__ __forceinline__ float fast_sigmoid(float x) {
    // 1/(1+exp(-x)) via v_exp (exp2) + v_rcp; ~1 ulp, fine vs 2e-1 threshold
    float e = __builtin_amdgcn_exp2f(x * -1.44269504088896340736f);
    return __builtin_amdgcn_rcpf(1.0f + e);
}

// ---------------------------------------------------------------------------
// Phase 1: u[t_local*32 + b][n] = DT * sum_i inp[b][t0+t_local][i] * B[n][i]
// 64x64 output tile per block, K=64 fully staged in LDS (transposed [k][m]).
// ---------------------------------------------------------------------------
__global__ __launch_bounds__(256) void pre_gemm(const float* __restrict__ inp,
                                                const float* __restrict__ Bm,
                                                float* __restrict__ u,
                                                int t0, int rows) {
    __shared__ __align__(16) float At[64][68];
    __shared__ __align__(16) float Bt[64][68];
    const int tid = threadIdx.x;
    const int c4  = (tid & 15) * 4;   // k offset (0..60)
    const int rq  = tid >> 4;         // 0..15
    const int mbase = blockIdx.x * 64;
    const int nbase = blockIdx.y * 64;

    #pragma unroll
    for (int rr = 0; rr < 4; ++rr) {
        const int rloc = rr * 16 + rq;
        const int mr = mbase + rloc;
        float4 a = make_float4(0.f, 0.f, 0.f, 0.f);
        if (mr < rows) {
            const int b  = mr & 31;
            const int tl = mr >> 5;
            a = *(const float4*)(inp + ((size_t)b * TSTEPS + (t0 + tl)) * IDIM + c4);
        }
        At[c4 + 0][rloc] = a.x; At[c4 + 1][rloc] = a.y;
        At[c4 + 2][rloc] = a.z; At[c4 + 3][rloc] = a.w;
        const int n = nbase + rloc;
        float4 bb = *(const float4*)(Bm + (size_t)n * IDIM + c4);
        Bt[c4 + 0][rloc] = bb.x; Bt[c4 + 1][rloc] = bb.y;
        Bt[c4 + 2][rloc] = bb.z; Bt[c4 + 3][rloc] = bb.w;
    }
    __syncthreads();

    const int m4 = (tid >> 4) * 4;
    const int n4 = (tid & 15) * 4;
    float acc[4][4];
    #pragma unroll
    for (int i = 0; i < 4; ++i)
        #pragma unroll
        for (int j = 0; j < 4; ++j) acc[i][j] = 0.f;

    #pragma unroll 8
    for (int k = 0; k < 64; ++k) {
        float4 a = *(const float4*)&At[k][m4];
        float4 w = *(const float4*)&Bt[k][n4];
        float av[4] = {a.x, a.y, a.z, a.w};
        float wv[4] = {w.x, w.y, w.z, w.w};
        #pragma unroll
        for (int i = 0; i < 4; ++i)
            #pragma unroll
            for (int j = 0; j < 4; ++j)
                acc[i][j] = fmaf(av[i], wv[j], acc[i][j]);
    }

    #pragma unroll
    for (int i = 0; i < 4; ++i) {
        const int mr = mbase + m4 + i;
        if (mr < rows) {
            float4 o = make_float4(acc[i][0] * 0.1f, acc[i][1] * 0.1f,
                                   acc[i][2] * 0.1f, acc[i][3] * 0.1f);
            *(float4*)(u + (size_t)mr * NDIM + nbase + n4) = o;
        }
    }
}

// ---------------------------------------------------------------------------
// Phase 2: the serial scan. One block per trial (32 blocks, 256 threads).
// Thread owns 16 contiguous n; m,n rows live in registers (~260 VGPR).
// proj (8 floats) reduced per step: wave butterfly -> LDS -> wave0 -> bcast.
// ---------------------------------------------------------------------------
__global__ __launch_bounds__(256, 1) void scan_kernel(const float* __restrict__ mmat,
                                                      const float* __restrict__ nmat,
                                                      const float* __restrict__ u,
                                                      float* __restrict__ xseq,
                                                      float* __restrict__ xstate,
                                                      int t0, int tc) {
    const int b   = blockIdx.x;
    const int tid = threadIdx.x;
    const int j0  = tid * 16;

    __shared__ __align__(16) float wlds[32];
    __shared__ __align__(16) float projlds[8];

    float nm[16][8], mmr[16][8], x[16];
    const float4* np4 = (const float4*)(nmat + (size_t)j0 * RDIM);
    const float4* mp4 = (const float4*)(mmat + (size_t)j0 * RDIM);
    const float mscale = 0.1f / 4096.0f;   // DT / N folded into m
    #pragma unroll
    for (int j = 0; j < 16; ++j) {
        float4 a = np4[j * 2], c = np4[j * 2 + 1];
        nm[j][0] = a.x; nm[j][1] = a.y; nm[j][2] = a.z; nm[j][3] = a.w;
        nm[j][4] = c.x; nm[j][5] = c.y; nm[j][6] = c.z; nm[j][7] = c.w;
        float4 d = mp4[j * 2], e = mp4[j * 2 + 1];
        mmr[j][0] = d.x * mscale; mmr[j][1] = d.y * mscale;
        mmr[j][2] = d.z * mscale; mmr[j][3] = d.w * mscale;
        mmr[j][4] = e.x * mscale; mmr[j][5] = e.y * mscale;
        mmr[j][6] = e.z * mscale; mmr[j][7] = e.w * mscale;
    }

    if (t0 == 0) {
        #pragma unroll
        for (int j = 0; j < 16; ++j) x[j] = 0.0f;
        float* z = xseq + (size_t)b * (TSTEPS + 1) * NDIM + j0;  // x_seq[b][0][:]=0
        #pragma unroll
        for (int q = 0; q < 4; ++q) *(float4*)(z + q * 4) = make_float4(0.f, 0.f, 0.f, 0.f);
    } else {
        const float* xs = xstate + (size_t)b * NDIM + j0;
        #pragma unroll
        for (int q = 0; q < 4; ++q) {
            float4 v = *(const float4*)(xs + q * 4);
            x[q * 4 + 0] = v.x; x[q * 4 + 1] = v.y; x[q * 4 + 2] = v.z; x[q * 4 + 3] = v.w;
        }
    }

    for (int tl = 0; tl < tc; ++tl) {
        // load u early; first use is ~600 cyc later (after the reduction)
        const float* up = u + ((size_t)tl * BTRIALS + b) * NDIM + j0;
        float uv[16];
        #pragma unroll
        for (int q = 0; q < 4; ++q) {
            float4 v = *(const float4*)(up + q * 4);
            uv[q * 4 + 0] = v.x; uv[q * 4 + 1] = v.y; uv[q * 4 + 2] = v.z; uv[q * 4 + 3] = v.w;
        }

        // sigmoid + partial proj
        float part[8];
        #pragma unroll
        for (int r = 0; r < 8; ++r) part[r] = 0.0f;
        #pragma unroll
        for (int j = 0; j < 16; ++j) {
            float s = fast_sigmoid(x[j]);
            #pragma unroll
            for (int r = 0; r < 8; ++r) part[r] = fmaf(s, nm[j][r], part[r]);
        }

        // 64-lane butterfly on 8 values
        #pragma unroll
        for (int r = 0; r < 8; ++r) {
            float v = part[r];
            v += __shfl_xor(v, 1);
            v += __shfl_xor(v, 2);
            v += __shfl_xor(v, 4);
            v += __shfl_xor(v, 8);
            v += __shfl_xor(v, 16);
            v += __shfl_xor(v, 32);
            part[r] = v;
        }
        const int lane = tid & 63;
        const int wv   = tid >> 6;
        if (lane == 0) {
            #pragma unroll
            for (int r = 0; r < 8; ++r) wlds[wv * 8 + r] = part[r];
        }
        __syncthreads();
        if (tid < 64) {  // whole wave executes -> shfl sources well-defined
            float v = (tid < 32) ? wlds[tid] : 0.0f;
            v += __shfl_xor(v, 8);   // fold wave bit 0
            v += __shfl_xor(v, 16);  // fold wave bit 1
            if (tid < 8) projlds[tid] = v;
        }
        __syncthreads();

        float proj[8];
        {
            float4 p0 = *(const float4*)&projlds[0];
            float4 p1 = *(const float4*)&projlds[4];
            proj[0] = p0.x; proj[1] = p0.y; proj[2] = p0.z; proj[3] = p0.w;
            proj[4] = p1.x; proj[5] = p1.y; proj[6] = p1.z; proj[7] = p1.w;
        }

        float* xrow = xseq + ((size_t)b * (TSTEPS + 1) + (t0 + tl + 1)) * NDIM + j0;
        #pragma unroll
        for (int j = 0; j < 16; ++j) {
            float rec = proj[0] * mmr[j][0];
            #pragma unroll
            for (int r = 1; r < 8; ++r) rec = fmaf(proj[r], mmr[j][r], rec);
            x[j] = fmaf(0.9f, x[j], rec + uv[j]);  // (1-DT)x + DT*rec + DT*u (scales folded)
        }
        #pragma unroll
        for (int q = 0; q < 4; ++q) {
            *(float4*)(xrow + q * 4) =
                make_float4(x[q * 4 + 0], x[q * 4 + 1], x[q * 4 + 2], x[q * 4 + 3]);
        }
    }

    // persist state for next chunk
    float* xs = xstate + (size_t)b * NDIM + j0;
    #pragma unroll
    for (int q = 0; q < 4; ++q)
        *(float4*)(xs + q * 4) =
            make_float4(x[q * 4 + 0], x[q * 4 + 1], x[q * 4 + 2], x[q * 4 + 3]);
}

// ---------------------------------------------------------------------------
// Phase 3: y[b][t][o] = sum_n sigmoid(x_seq[b][t+1][n]) * W[o][n]
// M=16384 rows, 64 rows/block, K staged in 64-chunks ([k][m] / [k][o] in LDS).
// ---------------------------------------------------------------------------
__global__ __launch_bounds__(256) void y_gemm(const float* __restrict__ xseq,
                                              const float* __restrict__ Wm,
                                              float* __restrict__ yout) {
    __shared__ __align__(16) float Sg[64][68];
    __shared__ __align__(16) float Wt[64][68];
    const int tid = threadIdx.x;
    const int c4  = (tid & 15) * 4;
    const int rq  = tid >> 4;
    const int mbase = blockIdx.x * 64;
    const int m4 = (tid >> 4) * 4;
    const int o4 = (tid & 15) * 4;

    float acc[4][4];
    #pragma unroll
    for (int i = 0; i < 4; ++i)
        #pragma unroll
        for (int j = 0; j < 4; ++j) acc[i][j] = 0.f;

    for (int kc = 0; kc < NDIM; kc += 64) {
        __syncthreads();
        #pragma unroll
        for (int rr = 0; rr < 4; ++rr) {
            const int rloc = rr * 16 + rq;
            const int m = mbase + rloc;          // m = b*512 + t
            const int brow = m >> 9;
            float4 a = *(const float4*)(xseq + (size_t)(m + brow + 1) * NDIM + kc + c4);
            Sg[c4 + 0][rloc] = fast_sigmoid(a.x);
            Sg[c4 + 1][rloc] = fast_sigmoid(a.y);
            Sg[c4 + 2][rloc] = fast_sigmoid(a.z);
            Sg[c4 + 3][rloc] = fast_sigmoid(a.w);
            float4 w = *(const float4*)(Wm + (size_t)rloc * NDIM + kc + c4);
            Wt[c4 + 0][rloc] = w.x; Wt[c4 + 1][rloc] = w.y;
            Wt[c4 + 2][rloc] = w.z; Wt[c4 + 3][rloc] = w.w;
        }
        __syncthreads();
        #pragma unroll 8
        for (int k = 0; k < 64; ++k) {
            float4 a = *(const float4*)&Sg[k][m4];
            float4 w = *(const float4*)&Wt[k][o4];
            float av[4] = {a.x, a.y, a.z, a.w};
            float wv[4] = {w.x, w.y, w.z, w.w};
            #pragma unroll
            for (int i = 0; i < 4; ++i)
                #pragma unroll
                for (int j = 0; j < 4; ++j)
                    acc[i][j] = fmaf(av[i], wv[j], acc[i][j]);
        }
    }

    #pragma unroll
    for (int i = 0; i < 4; ++i) {
        *(float4*)(yout + (size_t)(mbase + m4 + i) * ODIM + o4) =
            make_float4(acc[i][0], acc[i][1], acc[i][2], acc[i][3]);
    }
}

extern "C" void kernel_launch(void* const* d_in, const int* in_sizes, int n_in,
                              void* d_out, int out_size, void* d_ws, size_t ws_size,
                              hipStream_t stream) {
    const float* inp = (const float*)d_in[0];   // [32][512][64]
    const float* Bm  = (const float*)d_in[1];   // [4096][64]
    const float* Wm  = (const float*)d_in[2];   // [64][4096]
    const float* mm  = (const float*)d_in[3];   // [4096][8]
    const float* nm  = (const float*)d_in[4];   // [4096][8]

    float* out  = (float*)d_out;
    float* xseq = out;                                          // [32][513][4096]
    float* yout = out + (size_t)BTRIALS * (TSTEPS + 1) * NDIM;  // [32][512][64]

    float* xstate = (float*)d_ws;                       // [32][4096]
    float* ubuf   = xstate + (size_t)BTRIALS * NDIM;    // [Tc][32][4096]

    const size_t xbytes  = (size_t)BTRIALS * NDIM * sizeof(float);
    const size_t perstep = (size_t)BTRIALS * NDIM * sizeof(float);
    size_t avail = (ws_size > xbytes) ? (ws_size - xbytes) : 0;
    int Tc = (int)(avail / perstep);
    if (Tc > TSTEPS) Tc = TSTEPS;
    if (Tc < 1) Tc = 1;

    for (int t0 = 0; t0 < TSTEPS; t0 += Tc) {
        const int tc = (TSTEPS - t0 < Tc) ? (TSTEPS - t0) : Tc;
        const int rows = tc * BTRIALS;
        dim3 g1((rows + 63) / 64, NDIM / 64);
        pre_gemm<<<g1, 256, 0, stream>>>(inp, Bm, ubuf, t0, rows);
        scan_kernel<<<BTRIALS, 256, 0, stream>>>(mm, nm, ubuf, xseq, xstate, t0, tc);
    }
    y_gemm<<<(BTRIALS * TSTEPS) / 64, 256, 0, stream>>>(xseq, Wm, yout);
}

// Round 2
// 1145.868 us; speedup vs baseline: 1.3400x; 1.3400x over previous
//
#include <hip/hip_runtime.h>

static constexpr int BTRIALS = 32;
static constexpr int TSTEPS  = 512;
static constexpr int IDIM    = 64;
static constexpr int NDIM    = 4096;
static constexpr int RDIM    = 8;
static constexpr int ODIM    = 64;

__device__ __forceinline__ float fast_sigmoid(float x) {
    float e = __builtin_amdgcn_exp2f(x * -1.44269504088896340736f);
    return __builtin_amdgcn_rcpf(1.0f + e);
}

// one DPP accumulate step: v += dpp_move(v) with 0-fill for invalid lanes
template <int CTRL, int RMASK>
__device__ __forceinline__ float dpp_add(float v) {
    int moved = __builtin_amdgcn_update_dpp(0, __float_as_int(v), CTRL, RMASK, 0xf, true);
    return v + __int_as_float(moved);
}

// full 64-lane sum -> result valid in lane 63 (classic GCN DPP reduce)
__device__ __forceinline__ float wave_reduce_to_lane63(float v) {
    v = dpp_add<0x111, 0xf>(v);  // row_shr:1
    v = dpp_add<0x112, 0xf>(v);  // row_shr:2
    v = dpp_add<0x114, 0xf>(v);  // row_shr:4
    v = dpp_add<0x118, 0xf>(v);  // row_shr:8
    v = dpp_add<0x142, 0xa>(v);  // row_bcast:15 -> rows 1,3
    v = dpp_add<0x143, 0xc>(v);  // row_bcast:31 -> rows 2,3
    return v;
}

// ---------------------------------------------------------------------------
// Phase 1: u[t_local*32 + b][n] = DT * sum_i inp[b][t0+t_local][i] * B[n][i]
// ---------------------------------------------------------------------------
__global__ __launch_bounds__(256) void pre_gemm(const float* __restrict__ inp,
                                                const float* __restrict__ Bm,
                                                float* __restrict__ u,
                                                int t0, int rows) {
    __shared__ __align__(16) float At[64][68];
    __shared__ __align__(16) float Bt[64][68];
    const int tid = threadIdx.x;
    const int c4  = (tid & 15) * 4;
    const int rq  = tid >> 4;
    const int mbase = blockIdx.x * 64;
    const int nbase = blockIdx.y * 64;

    #pragma unroll
    for (int rr = 0; rr < 4; ++rr) {
        const int rloc = rr * 16 + rq;
        const int mr = mbase + rloc;
        float4 a = make_float4(0.f, 0.f, 0.f, 0.f);
        if (mr < rows) {
            const int b  = mr & 31;
            const int tl = mr >> 5;
            a = *(const float4*)(inp + ((size_t)b * TSTEPS + (t0 + tl)) * IDIM + c4);
        }
        At[c4 + 0][rloc] = a.x; At[c4 + 1][rloc] = a.y;
        At[c4 + 2][rloc] = a.z; At[c4 + 3][rloc] = a.w;
        const int n = nbase + rloc;
        float4 bb = *(const float4*)(Bm + (size_t)n * IDIM + c4);
        Bt[c4 + 0][rloc] = bb.x; Bt[c4 + 1][rloc] = bb.y;
        Bt[c4 + 2][rloc] = bb.z; Bt[c4 + 3][rloc] = bb.w;
    }
    __syncthreads();

    const int m4 = (tid >> 4) * 4;
    const int n4 = (tid & 15) * 4;
    float acc[4][4];
    #pragma unroll
    for (int i = 0; i < 4; ++i)
        #pragma unroll
        for (int j = 0; j < 4; ++j) acc[i][j] = 0.f;

    #pragma unroll 8
    for (int k = 0; k < 64; ++k) {
        float4 a = *(const float4*)&At[k][m4];
        float4 w = *(const float4*)&Bt[k][n4];
        float av[4] = {a.x, a.y, a.z, a.w};
        float wv[4] = {w.x, w.y, w.z, w.w};
        #pragma unroll
        for (int i = 0; i < 4; ++i)
            #pragma unroll
            for (int j = 0; j < 4; ++j)
                acc[i][j] = fmaf(av[i], wv[j], acc[i][j]);
    }

    #pragma unroll
    for (int i = 0; i < 4; ++i) {
        const int mr = mbase + m4 + i;
        if (mr < rows) {
            float4 o = make_float4(acc[i][0] * 0.1f, acc[i][1] * 0.1f,
                                   acc[i][2] * 0.1f, acc[i][3] * 0.1f);
            *(float4*)(u + (size_t)mr * NDIM + nbase + n4) = o;
        }
    }
}

// ---------------------------------------------------------------------------
// Phase 2: serial scan. One block per trial (32 blocks x 512 threads).
// Thread owns 8 contiguous n -> params = 128 floats/thread, fits in VGPRs
// (no reload from global inside the loop). Reduction: DPP butterfly ->
// lane63 LDS write -> barrier -> wave0 fold (1 ds_read + 3 shfl) -> barrier
// -> 8-float broadcast read. u prefetched one full step ahead.
// ---------------------------------------------------------------------------
__global__ __launch_bounds__(512, 2) void scan_kernel(const float* __restrict__ mmat,
                                                      const float* __restrict__ nmat,
                                                      const float* __restrict__ u,
                                                      float* __restrict__ xseq,
                                                      float* __restrict__ xstate,
                                                      int t0, int tc) {
    const int b    = blockIdx.x;
    const int tid  = threadIdx.x;
    const int j0   = tid * 8;
    const int lane = tid & 63;
    const int wv   = tid >> 6;   // 0..7

    __shared__ __align__(16) float wlds[64];   // 8 waves x 8 partials
    __shared__ __align__(16) float projb[8];

    float nm[8][8], mmr[8][8], x[8];
    const float4* np4 = (const float4*)(nmat + (size_t)j0 * RDIM);
    const float4* mp4 = (const float4*)(mmat + (size_t)j0 * RDIM);
    const float mscale = 0.1f / 4096.0f;   // DT / N folded into m
    #pragma unroll
    for (int j = 0; j < 8; ++j) {
        float4 a = np4[j * 2], c = np4[j * 2 + 1];
        nm[j][0] = a.x; nm[j][1] = a.y; nm[j][2] = a.z; nm[j][3] = a.w;
        nm[j][4] = c.x; nm[j][5] = c.y; nm[j][6] = c.z; nm[j][7] = c.w;
        float4 d = mp4[j * 2], e = mp4[j * 2 + 1];
        mmr[j][0] = d.x * mscale; mmr[j][1] = d.y * mscale;
        mmr[j][2] = d.z * mscale; mmr[j][3] = d.w * mscale;
        mmr[j][4] = e.x * mscale; mmr[j][5] = e.y * mscale;
        mmr[j][6] = e.z * mscale; mmr[j][7] = e.w * mscale;
    }

    if (t0 == 0) {
        #pragma unroll
        for (int j = 0; j < 8; ++j) x[j] = 0.0f;
        float* z = xseq + (size_t)b * (TSTEPS + 1) * NDIM + j0;
        *(float4*)(z + 0) = make_float4(0.f, 0.f, 0.f, 0.f);
        *(float4*)(z + 4) = make_float4(0.f, 0.f, 0.f, 0.f);
    } else {
        const float* xs = xstate + (size_t)b * NDIM + j0;
        float4 v0 = *(const float4*)(xs + 0);
        float4 v1 = *(const float4*)(xs + 4);
        x[0] = v0.x; x[1] = v0.y; x[2] = v0.z; x[3] = v0.w;
        x[4] = v1.x; x[5] = v1.y; x[6] = v1.z; x[7] = v1.w;
    }

    // preload u for step 0
    float uv[8];
    {
        const float* up = u + ((size_t)0 * BTRIALS + b) * NDIM + j0;
        float4 v0 = *(const float4*)(up + 0);
        float4 v1 = *(const float4*)(up + 4);
        uv[0] = v0.x; uv[1] = v0.y; uv[2] = v0.z; uv[3] = v0.w;
        uv[4] = v1.x; uv[5] = v1.y; uv[6] = v1.z; uv[7] = v1.w;
    }

    for (int tl = 0; tl < tc; ++tl) {
        // prefetch u for NEXT step (in flight across this whole step)
        const int tn = (tl + 1 < tc) ? (tl + 1) : tl;
        const float* upn = u + ((size_t)tn * BTRIALS + b) * NDIM + j0;
        float4 pf0 = *(const float4*)(upn + 0);
        float4 pf1 = *(const float4*)(upn + 4);

        // sigmoid + partial projections (64 FMA/thread)
        float part[8];
        #pragma unroll
        for (int r = 0; r < 8; ++r) part[r] = 0.0f;
        #pragma unroll
        for (int j = 0; j < 8; ++j) {
            float s = fast_sigmoid(x[j]);
            #pragma unroll
            for (int r = 0; r < 8; ++r) part[r] = fmaf(s, nm[j][r], part[r]);
        }

        // intra-wave: DPP butterfly (pure VALU, no lgkm)
        #pragma unroll
        for (int r = 0; r < 8; ++r) part[r] = wave_reduce_to_lane63(part[r]);

        if (lane == 63) {
            *(float4*)&wlds[wv * 8 + 0] = make_float4(part[0], part[1], part[2], part[3]);
            *(float4*)&wlds[wv * 8 + 4] = make_float4(part[4], part[5], part[6], part[7]);
        }
        __syncthreads();
        if (tid < 64) {  // whole wave0: fold 8 wave-partials (idx = w*8 + r)
            float v = wlds[tid];
            v += __shfl_xor(v, 8);
            v += __shfl_xor(v, 16);
            v += __shfl_xor(v, 32);
            if (tid < 8) projb[tid] = v;
        }
        __syncthreads();

        float4 p0 = *(const float4*)&projb[0];
        float4 p1 = *(const float4*)&projb[4];
        float proj[8] = {p0.x, p0.y, p0.z, p0.w, p1.x, p1.y, p1.z, p1.w};

        float* xrow = xseq + ((size_t)b * (TSTEPS + 1) + (t0 + tl + 1)) * NDIM + j0;
        #pragma unroll
        for (int j = 0; j < 8; ++j) {
            float rec = proj[0] * mmr[j][0];
            #pragma unroll
            for (int r = 1; r < 8; ++r) rec = fmaf(proj[r], mmr[j][r], rec);
            x[j] = fmaf(0.9f, x[j], rec + uv[j]);
        }
        *(float4*)(xrow + 0) = make_float4(x[0], x[1], x[2], x[3]);
        *(float4*)(xrow + 4) = make_float4(x[4], x[5], x[6], x[7]);

        uv[0] = pf0.x; uv[1] = pf0.y; uv[2] = pf0.z; uv[3] = pf0.w;
        uv[4] = pf1.x; uv[5] = pf1.y; uv[6] = pf1.z; uv[7] = pf1.w;
    }

    float* xs = xstate + (size_t)b * NDIM + j0;
    *(float4*)(xs + 0) = make_float4(x[0], x[1], x[2], x[3]);
    *(float4*)(xs + 4) = make_float4(x[4], x[5], x[6], x[7]);
}

// ---------------------------------------------------------------------------
// Phase 3: y[b][t][o] = sum_n sigmoid(x_seq[b][t+1][n]) * W[o][n]
// ---------------------------------------------------------------------------
__global__ __launch_bounds__(256) void y_gemm(const float* __restrict__ xseq,
                                              const float* __restrict__ Wm,
                                              float* __restrict__ yout) {
    __shared__ __align__(16) float Sg[64][68];
    __shared__ __align__(16) float Wt[64][68];
    const int tid = threadIdx.x;
    const int c4  = (tid & 15) * 4;
    const int rq  = tid >> 4;
    const int mbase = blockIdx.x * 64;
    const int m4 = (tid >> 4) * 4;
    const int o4 = (tid & 15) * 4;

    float acc[4][4];
    #pragma unroll
    for (int i = 0; i < 4; ++i)
        #pragma unroll
        for (int j = 0; j < 4; ++j) acc[i][j] = 0.f;

    for (int kc = 0; kc < NDIM; kc += 64) {
        __syncthreads();
        #pragma unroll
        for (int rr = 0; rr < 4; ++rr) {
            const int rloc = rr * 16 + rq;
            const int m = mbase + rloc;          // m = b*512 + t
            const int brow = m >> 9;
            float4 a = *(const float4*)(xseq + (size_t)(m + brow + 1) * NDIM + kc + c4);
            Sg[c4 + 0][rloc] = fast_sigmoid(a.x);
            Sg[c4 + 1][rloc] = fast_sigmoid(a.y);
            Sg[c4 + 2][rloc] = fast_sigmoid(a.z);
            Sg[c4 + 3][rloc] = fast_sigmoid(a.w);
            float4 w = *(const float4*)(Wm + (size_t)rloc * NDIM + kc + c4);
            Wt[c4 + 0][rloc] = w.x; Wt[c4 + 1][rloc] = w.y;
            Wt[c4 + 2][rloc] = w.z; Wt[c4 + 3][rloc] = w.w;
        }
        __syncthreads();
        #pragma unroll 8
        for (int k = 0; k < 64; ++k) {
            float4 a = *(const float4*)&Sg[k][m4];
            float4 w = *(const float4*)&Wt[k][o4];
            float av[4] = {a.x, a.y, a.z, a.w};
            float wv[4] = {w.x, w.y, w.z, w.w};
            #pragma unroll
            for (int i = 0; i < 4; ++i)
                #pragma unroll
                for (int j = 0; j < 4; ++j)
                    acc[i][j] = fmaf(av[i], wv[j], acc[i][j]);
        }
    }

    #pragma unroll
    for (int i = 0; i < 4; ++i) {
        *(float4*)(yout + (size_t)(mbase + m4 + i) * ODIM + o4) =
            make_float4(acc[i][0], acc[i][1], acc[i][2], acc[i][3]);
    }
}

extern "C" void kernel_launch(void* const* d_in, const int* in_sizes, int n_in,
                              void* d_out, int out_size, void* d_ws, size_t ws_size,
                              hipStream_t stream) {
    const float* inp = (const float*)d_in[0];   // [32][512][64]
    const float* Bm  = (const float*)d_in[1];   // [4096][64]
    const float* Wm  = (const float*)d_in[2];   // [64][4096]
    const float* mm  = (const float*)d_in[3];   // [4096][8]
    const float* nm  = (const float*)d_in[4];   // [4096][8]

    float* out  = (float*)d_out;
    float* xseq = out;                                          // [32][513][4096]
    float* yout = out + (size_t)BTRIALS * (TSTEPS + 1) * NDIM;  // [32][512][64]

    float* xstate = (float*)d_ws;                       // [32][4096]
    float* ubuf   = xstate + (size_t)BTRIALS * NDIM;    // [Tc][32][4096]

    const size_t xbytes  = (size_t)BTRIALS * NDIM * sizeof(float);
    const size_t perstep = (size_t)BTRIALS * NDIM * sizeof(float);
    size_t avail = (ws_size > xbytes) ? (ws_size - xbytes) : 0;
    int Tc = (int)(avail / perstep);
    if (Tc > TSTEPS) Tc = TSTEPS;
    if (Tc < 1) Tc = 1;

    for (int t0 = 0; t0 < TSTEPS; t0 += Tc) {
        const int tc = (TSTEPS - t0 < Tc) ? (TSTEPS - t0) : Tc;
        const int rows = tc * BTRIALS;
        dim3 g1((rows + 63) / 64, NDIM / 64);
        pre_gemm<<<g1, 256, 0, stream>>>(inp, Bm, ubuf, t0, rows);
        scan_kernel<<<BTRIALS, 512, 0, stream>>>(mm, nm, ubuf, xseq, xstate, t0, tc);
    }
    y_gemm<<<(BTRIALS * TSTEPS) / 64, 256, 0, stream>>>(xseq, Wm, yout);
}

// Round 3
// 1061.837 us; speedup vs baseline: 1.4460x; 1.0791x over previous
//
#include <hip/hip_runtime.h>

static constexpr int BTRIALS = 32;
static constexpr int TSTEPS  = 512;
static constexpr int IDIM    = 64;
static constexpr int NDIM    = 4096;
static constexpr int RDIM    = 8;
static constexpr int ODIM    = 64;

__device__ __forceinline__ float fast_sigmoid(float x) {
    float e = __builtin_amdgcn_exp2f(x * -1.44269504088896340736f);
    return __builtin_amdgcn_rcpf(1.0f + e);
}

// v += dpp_move(v), 0-fill invalid lanes
template <int CTRL, int RMASK>
__device__ __forceinline__ float dpp_add(float v) {
    int moved = __builtin_amdgcn_update_dpp(0, __float_as_int(v), CTRL, RMASK, 0xf, true);
    return v + __int_as_float(moved);
}

// full 64-lane sum -> valid in lane 63
__device__ __forceinline__ float wave_reduce_to_lane63(float v) {
    v = dpp_add<0x111, 0xf>(v);  // row_shr:1
    v = dpp_add<0x112, 0xf>(v);  // row_shr:2
    v = dpp_add<0x114, 0xf>(v);  // row_shr:4
    v = dpp_add<0x118, 0xf>(v);  // row_shr:8
    v = dpp_add<0x142, 0xa>(v);  // row_bcast:15 -> rows 1,3
    v = dpp_add<0x143, 0xc>(v);  // row_bcast:31 -> rows 2,3
    return v;
}

__device__ __forceinline__ short f2bf(float f) {
    unsigned u = __float_as_uint(f);
    u += 0x7FFFu + ((u >> 16) & 1u);   // RNE
    return (short)(u >> 16);
}

// ---------------------------------------------------------------------------
// Phase 1: u[t_local*32 + b][n] = DT * sum_i inp[b][t0+t_local][i] * B[n][i]
// (unchanged this round)
// ---------------------------------------------------------------------------
__global__ __launch_bounds__(256) void pre_gemm(const float* __restrict__ inp,
                                                const float* __restrict__ Bm,
                                                float* __restrict__ u,
                                                int t0, int rows) {
    __shared__ __align__(16) float At[64][68];
    __shared__ __align__(16) float Bt[64][68];
    const int tid = threadIdx.x;
    const int c4  = (tid & 15) * 4;
    const int rq  = tid >> 4;
    const int mbase = blockIdx.x * 64;
    const int nbase = blockIdx.y * 64;

    #pragma unroll
    for (int rr = 0; rr < 4; ++rr) {
        const int rloc = rr * 16 + rq;
        const int mr = mbase + rloc;
        float4 a = make_float4(0.f, 0.f, 0.f, 0.f);
        if (mr < rows) {
            const int b  = mr & 31;
            const int tl = mr >> 5;
            a = *(const float4*)(inp + ((size_t)b * TSTEPS + (t0 + tl)) * IDIM + c4);
        }
        At[c4 + 0][rloc] = a.x; At[c4 + 1][rloc] = a.y;
        At[c4 + 2][rloc] = a.z; At[c4 + 3][rloc] = a.w;
        const int n = nbase + rloc;
        float4 bb = *(const float4*)(Bm + (size_t)n * IDIM + c4);
        Bt[c4 + 0][rloc] = bb.x; Bt[c4 + 1][rloc] = bb.y;
        Bt[c4 + 2][rloc] = bb.z; Bt[c4 + 3][rloc] = bb.w;
    }
    __syncthreads();

    const int m4 = (tid >> 4) * 4;
    const int n4 = (tid & 15) * 4;
    float acc[4][4];
    #pragma unroll
    for (int i = 0; i < 4; ++i)
        #pragma unroll
        for (int j = 0; j < 4; ++j) acc[i][j] = 0.f;

    #pragma unroll 8
    for (int k = 0; k < 64; ++k) {
        float4 a = *(const float4*)&At[k][m4];
        float4 w = *(const float4*)&Bt[k][n4];
        float av[4] = {a.x, a.y, a.z, a.w};
        float wv[4] = {w.x, w.y, w.z, w.w};
        #pragma unroll
        for (int i = 0; i < 4; ++i)
            #pragma unroll
            for (int j = 0; j < 4; ++j)
                acc[i][j] = fmaf(av[i], wv[j], acc[i][j]);
    }

    #pragma unroll
    for (int i = 0; i < 4; ++i) {
        const int mr = mbase + m4 + i;
        if (mr < rows) {
            float4 o = make_float4(acc[i][0] * 0.1f, acc[i][1] * 0.1f,
                                   acc[i][2] * 0.1f, acc[i][3] * 0.1f);
            *(float4*)(u + (size_t)mr * NDIM + nbase + n4) = o;
        }
    }
}

// ---------------------------------------------------------------------------
// Phase 2: serial scan. 32 blocks x 512 threads, 8 n/thread.
// ONE barrier per step: wave partials go to double-buffered wlds[r*8+w];
// every wave folds the 8-wave groups with 3 DPP row_shr adds (clean in lane
// r*8+7), then v_readlane -> SGPR proj. Decay term precomputed pre-barrier.
// ---------------------------------------------------------------------------
__global__ __launch_bounds__(512, 2) void scan_kernel(const float* __restrict__ mmat,
                                                      const float* __restrict__ nmat,
                                                      const float* __restrict__ u,
                                                      float* __restrict__ xseq,
                                                      float* __restrict__ xstate,
                                                      int t0, int tc) {
    const int b    = blockIdx.x;
    const int tid  = threadIdx.x;
    const int j0   = tid * 8;
    const int lane = tid & 63;
    const int wv   = tid >> 6;   // 0..7

    __shared__ __align__(16) float wlds[2][64];   // [r*8 + w], double-buffered

    float nm[8][8], mmr[8][8], x[8];
    const float4* np4 = (const float4*)(nmat + (size_t)j0 * RDIM);
    const float4* mp4 = (const float4*)(mmat + (size_t)j0 * RDIM);
    const float mscale = 0.1f / 4096.0f;   // DT / N folded into m
    #pragma unroll
    for (int j = 0; j < 8; ++j) {
        float4 a = np4[j * 2], c = np4[j * 2 + 1];
        nm[j][0] = a.x; nm[j][1] = a.y; nm[j][2] = a.z; nm[j][3] = a.w;
        nm[j][4] = c.x; nm[j][5] = c.y; nm[j][6] = c.z; nm[j][7] = c.w;
        float4 d = mp4[j * 2], e = mp4[j * 2 + 1];
        mmr[j][0] = d.x * mscale; mmr[j][1] = d.y * mscale;
        mmr[j][2] = d.z * mscale; mmr[j][3] = d.w * mscale;
        mmr[j][4] = e.x * mscale; mmr[j][5] = e.y * mscale;
        mmr[j][6] = e.z * mscale; mmr[j][7] = e.w * mscale;
    }

    if (t0 == 0) {
        #pragma unroll
        for (int j = 0; j < 8; ++j) x[j] = 0.0f;
        float* z = xseq + (size_t)b * (TSTEPS + 1) * NDIM + j0;
        *(float4*)(z + 0) = make_float4(0.f, 0.f, 0.f, 0.f);
        *(float4*)(z + 4) = make_float4(0.f, 0.f, 0.f, 0.f);
    } else {
        const float* xs = xstate + (size_t)b * NDIM + j0;
        float4 v0 = *(const float4*)(xs + 0);
        float4 v1 = *(const float4*)(xs + 4);
        x[0] = v0.x; x[1] = v0.y; x[2] = v0.z; x[3] = v0.w;
        x[4] = v1.x; x[5] = v1.y; x[6] = v1.z; x[7] = v1.w;
    }

    float uv[8];
    {
        const float* up = u + ((size_t)0 * BTRIALS + b) * NDIM + j0;
        float4 v0 = *(const float4*)(up + 0);
        float4 v1 = *(const float4*)(up + 4);
        uv[0] = v0.x; uv[1] = v0.y; uv[2] = v0.z; uv[3] = v0.w;
        uv[4] = v1.x; uv[5] = v1.y; uv[6] = v1.z; uv[7] = v1.w;
    }

    for (int tl = 0; tl < tc; ++tl) {
        const int buf = tl & 1;
        // prefetch u for next step
        const int tn = (tl + 1 < tc) ? (tl + 1) : tl;
        const float* upn = u + ((size_t)tn * BTRIALS + b) * NDIM + j0;
        float4 pf0 = *(const float4*)(upn + 0);
        float4 pf1 = *(const float4*)(upn + 4);

        // partial projections
        float part[8];
        #pragma unroll
        for (int r = 0; r < 8; ++r) part[r] = 0.0f;
        #pragma unroll
        for (int j = 0; j < 8; ++j) {
            float s = fast_sigmoid(x[j]);
            #pragma unroll
            for (int r = 0; r < 8; ++r) part[r] = fmaf(s, nm[j][r], part[r]);
        }
        #pragma unroll
        for (int r = 0; r < 8; ++r) part[r] = wave_reduce_to_lane63(part[r]);

        if (lane == 63) {
            #pragma unroll
            for (int r = 0; r < 8; ++r) wlds[buf][r * 8 + wv] = part[r];
        }

        // decay + input (independent of proj) before the barrier
        float xd[8];
        #pragma unroll
        for (int j = 0; j < 8; ++j) xd[j] = fmaf(0.9f, x[j], uv[j]);

        __syncthreads();

        // fold 8 wave-partials per r: one ds_read + 3 DPP row_shr adds.
        // lane = r*8 + w; lanes r*8+7 are clean group sums (shr pollutes only
        // lower lanes; zero-fill protects lane 7 of each group-of-8 pair).
        float v = wlds[buf][lane];
        v = dpp_add<0x111, 0xf>(v);  // row_shr:1
        v = dpp_add<0x112, 0xf>(v);  // row_shr:2
        v = dpp_add<0x114, 0xf>(v);  // row_shr:4

        float ps[8];
        #pragma unroll
        for (int r = 0; r < 8; ++r)
            ps[r] = __int_as_float(__builtin_amdgcn_readlane(__float_as_int(v), r * 8 + 7));

        float* xrow = xseq + ((size_t)b * (TSTEPS + 1) + (t0 + tl + 1)) * NDIM + j0;
        #pragma unroll
        for (int j = 0; j < 8; ++j) {
            float acc = xd[j];
            #pragma unroll
            for (int r = 0; r < 8; ++r) acc = fmaf(ps[r], mmr[j][r], acc);
            x[j] = acc;
        }
        *(float4*)(xrow + 0) = make_float4(x[0], x[1], x[2], x[3]);
        *(float4*)(xrow + 4) = make_float4(x[4], x[5], x[6], x[7]);

        uv[0] = pf0.x; uv[1] = pf0.y; uv[2] = pf0.z; uv[3] = pf0.w;
        uv[4] = pf1.x; uv[5] = pf1.y; uv[6] = pf1.z; uv[7] = pf1.w;
    }

    float* xs = xstate + (size_t)b * NDIM + j0;
    *(float4*)(xs + 0) = make_float4(x[0], x[1], x[2], x[3]);
    *(float4*)(xs + 4) = make_float4(x[4], x[5], x[6], x[7]);
}

// ---------------------------------------------------------------------------
// Phase 3: y = sigmoid(xseq) @ W^T via bf16 MFMA 16x16x32. No LDS, no
// barriers: one wave per 16-row m-tile, 4 o-tiles (O=64) accumulated in f32.
// A[m][k]: m=lane&15, k=(lane>>4)*8+j  -> contiguous 8 floats per lane.
// B[k][o]=W[o][k]: o=lane&15, same k   -> contiguous 8 floats per lane.
// D: col=lane&15, row=(lane>>4)*4+reg.
// ---------------------------------------------------------------------------
typedef short v8s __attribute__((ext_vector_type(8)));
typedef float v4f __attribute__((ext_vector_type(4)));

__global__ __launch_bounds__(256) void y_gemm(const float* __restrict__ xseq,
                                              const float* __restrict__ Wm,
                                              float* __restrict__ yout) {
    const int tid  = threadIdx.x;
    const int lane = tid & 63;
    const int mt   = blockIdx.x * 4 + (tid >> 6);   // m-tile index, 16 rows each
    const int lm   = lane & 15;
    const int kq   = lane >> 4;                     // 0..3

    const int m = mt * 16 + lm;                     // y row = b*512 + t
    const int g = m + (m >> 9) + 1;                 // xseq row (skip x0 per trial)
    const float* pa = xseq + (size_t)g * NDIM + kq * 8;
    const float* pw = Wm + (size_t)lm * NDIM + kq * 8;

    v4f acc[4];
    #pragma unroll
    for (int ot = 0; ot < 4; ++ot) acc[ot] = (v4f){0.f, 0.f, 0.f, 0.f};

    for (int kc = 0; kc < NDIM; kc += 32) {
        float4 a0 = *(const float4*)(pa + kc);
        float4 a1 = *(const float4*)(pa + kc + 4);
        v8s af;
        af[0] = f2bf(fast_sigmoid(a0.x)); af[1] = f2bf(fast_sigmoid(a0.y));
        af[2] = f2bf(fast_sigmoid(a0.z)); af[3] = f2bf(fast_sigmoid(a0.w));
        af[4] = f2bf(fast_sigmoid(a1.x)); af[5] = f2bf(fast_sigmoid(a1.y));
        af[6] = f2bf(fast_sigmoid(a1.z)); af[7] = f2bf(fast_sigmoid(a1.w));
        #pragma unroll
        for (int ot = 0; ot < 4; ++ot) {
            const float* pwo = pw + (size_t)ot * 16 * NDIM + kc;
            float4 w0 = *(const float4*)(pwo);
            float4 w1 = *(const float4*)(pwo + 4);
            v8s bf;
            bf[0] = f2bf(w0.x); bf[1] = f2bf(w0.y);
            bf[2] = f2bf(w0.z); bf[3] = f2bf(w0.w);
            bf[4] = f2bf(w1.x); bf[5] = f2bf(w1.y);
            bf[6] = f2bf(w1.z); bf[7] = f2bf(w1.w);
            acc[ot] = __builtin_amdgcn_mfma_f32_16x16x32_bf16(af, bf, acc[ot], 0, 0, 0);
        }
    }

    #pragma unroll
    for (int ot = 0; ot < 4; ++ot) {
        #pragma unroll
        for (int r = 0; r < 4; ++r) {
            const int row = mt * 16 + kq * 4 + r;
            yout[(size_t)row * ODIM + ot * 16 + lm] = acc[ot][r];
        }
    }
}

extern "C" void kernel_launch(void* const* d_in, const int* in_sizes, int n_in,
                              void* d_out, int out_size, void* d_ws, size_t ws_size,
                              hipStream_t stream) {
    const float* inp = (const float*)d_in[0];   // [32][512][64]
    const float* Bm  = (const float*)d_in[1];   // [4096][64]
    const float* Wm  = (const float*)d_in[2];   // [64][4096]
    const float* mm  = (const float*)d_in[3];   // [4096][8]
    const float* nm  = (const float*)d_in[4];   // [4096][8]

    float* out  = (float*)d_out;
    float* xseq = out;                                          // [32][513][4096]
    float* yout = out + (size_t)BTRIALS * (TSTEPS + 1) * NDIM;  // [32][512][64]

    float* xstate = (float*)d_ws;                       // [32][4096]
    float* ubuf   = xstate + (size_t)BTRIALS * NDIM;    // [Tc][32][4096]

    const size_t xbytes  = (size_t)BTRIALS * NDIM * sizeof(float);
    const size_t perstep = (size_t)BTRIALS * NDIM * sizeof(float);
    size_t avail = (ws_size > xbytes) ? (ws_size - xbytes) : 0;
    int Tc = (int)(avail / perstep);
    if (Tc > TSTEPS) Tc = TSTEPS;
    if (Tc < 1) Tc = 1;

    for (int t0 = 0; t0 < TSTEPS; t0 += Tc) {
        const int tc = (TSTEPS - t0 < Tc) ? (TSTEPS - t0) : Tc;
        const int rows = tc * BTRIALS;
        dim3 g1((rows + 63) / 64, NDIM / 64);
        pre_gemm<<<g1, 256, 0, stream>>>(inp, Bm, ubuf, t0, rows);
        scan_kernel<<<BTRIALS, 512, 0, stream>>>(mm, nm, ubuf, xseq, xstate, t0, tc);
    }
    y_gemm<<<(BTRIALS * TSTEPS) / 64, 256, 0, stream>>>(xseq, Wm, yout);
}